// Round 12
// baseline (246.601 us; speedup 1.0000x reference)
//
#include <hip/hip_runtime.h>
#include <cstdint>
#include <cstddef>

#define N_NODES 100000
#define N_EDGES 3200000
#define N_FEAT  512
#define HIDDEN  16
#define NBUCK   ((N_NODES + 127) / 128)   // 782 buckets of 128 rows
#define BCAP    5120                      // slots/bucket; mean 4092, +16 sigma
#define CHUNK   2048                      // edges per binscatter role-block
#define NGB     ((N_NODES + 63) / 64)     // 1563 gemm role-blocks (64 rows)
#define NBS     ((N_EDGES + CHUNK - 1) / CHUNK)  // 1563 binscatter role-blocks

static_assert(NGB == NBS, "1:1 parity interleave requires equal role counts");

// ---------------------------------------------------------------------------
// async global -> LDS, 16B per lane. LDS dest is wave-uniform base + lane*16.
__device__ __forceinline__ void gload_lds16(const float* g, void* lds) {
  __builtin_amdgcn_global_load_lds(
      (const __attribute__((address_space(1))) void*)g,
      (__attribute__((address_space(3))) void*)lds, 16, 0, 0);
}

// ---------------------------------------------------------------------------
// Prep: zero bucket cursors (replaces rocclr fillBuffer).
__global__ __launch_bounds__(256)
void k_prep(int* __restrict__ cursor) {
  const int i = blockIdx.x * 256 + threadIdx.x;
  if (i < NBUCK) cursor[i] = 0;
}

// ---------------------------------------------------------------------------
// MEGA3 (1:1 parity interleave, 16 KB union LDS -> 8 blocks/CU, 32 waves/CU):
//   even blocks -> GEMM role (gid = bid>>1)
//   odd  blocks -> stash-free binscatter role (bsid = bid>>1)
//
// GEMM role: xw[r][c] = sum_k x[r][k]*W1[k][c]. 4 waves split K (128 each);
// K-chunk = 8 floats (2 quads). Per-wave double-buffered 2 KB stage filled by
// 2x gload_lds16, counted vmcnt(2), no intra-loop barriers. Swizzle: LDS slot
// (row r, s) holds global quad s ^ ((r>>2)&1); inverse on global source;
// read addr 2l + (g ^ ((l>>2)&1)) covers all 8 bank groups x 8 lanes (b128
// conflict-free). Cross-wave LDS reduce at the end.
//
// binscatter role (3.1 KB): phase 1 LDS histogram of row>>7; phase 2 ~780
// block-aggregated returned cursor atomics, hist := base in place; phase 3
// re-read inputs (L2-hot), off = atomicAdd(&hist[b],1) = base+rank, write
// packed {col | (row&127)<<20, val_bits}.
__global__ __launch_bounds__(256)
void k_mega3(const float* __restrict__ x, const float* __restrict__ W1,
             float* __restrict__ xw, const int* __restrict__ rows,
             const int* __restrict__ cols, const float* __restrict__ vals,
             int* __restrict__ cursor, int2* __restrict__ binned) {
  __shared__ __align__(16) char smem[16384];
  const int t = threadIdx.x;

  if ((blockIdx.x & 1) == 0) {
    // ---------------- GEMM role ----------------
    float4 (*xs)[2][128] = reinterpret_cast<float4 (*)[2][128]>(smem);
    const int l = t & 63;
    const int w = __builtin_amdgcn_readfirstlane(t >> 6);
    const int rbase = (blockIdx.x >> 1) * 64;
    const int kbase0 = w * 128;

    float acc[16];
#pragma unroll
    for (int c = 0; c < 16; ++c) acc[c] = 0.f;

    // write-side: gload i, lane l -> linear float4 idx = i*64 + l
    //   r = i*32 + (l>>1), s = l&1, global quad g = s ^ ((r>>2)&1)
    const int r0 = (l >> 1);                 // row within 32-row half
    const int s0 = l & 1;

    auto STAGE = [&](int b, int ck) {
      const int kb = kbase0 + ck * 8;
#pragma unroll
      for (int i = 0; i < 2; ++i) {
        const int r = i * 32 + r0;
        const int g = s0 ^ ((r >> 2) & 1);   // inverse swizzle on source
        int grow = rbase + r;
        if (grow >= N_NODES) grow = N_NODES - 1;   // clamp: fixed instr count
        gload_lds16(x + (size_t)grow * N_FEAT + kb + g * 4, &xs[w][b][i * 64]);
      }
    };

    const int rsw = (l >> 2) & 1;            // read swizzle for row l
    auto COMPUTE = [&](int b, int ck) {
      const int kb = kbase0 + ck * 8;
#pragma unroll
      for (int g = 0; g < 2; ++g) {
        float4 xv = xs[w][b][l * 2 + (g ^ rsw)];
        float xe[4] = {xv.x, xv.y, xv.z, xv.w};
#pragma unroll
        for (int j = 0; j < 4; ++j) {
          const float* wrow = W1 + (size_t)(kb + g * 4 + j) * 16;  // s_load
#pragma unroll
          for (int c = 0; c < 16; ++c)
            acc[c] = fmaf(xe[j], wrow[c], acc[c]);
        }
      }
    };

    STAGE(0, 0);
#pragma unroll 1
    for (int ck = 0; ck < 16; ++ck) {
      const int b = ck & 1;
      if (ck + 1 < 16) {
        STAGE(b ^ 1, ck + 1);
        asm volatile("s_waitcnt vmcnt(2)" ::: "memory");  // chunk ck resident
      } else {
        asm volatile("s_waitcnt vmcnt(0)" ::: "memory");
      }
      COMPUTE(b, ck);
    }

    // cross-wave reduce: wave w parks acc in its 4 KB region (both buffers)
    float4* red = &xs[w][0][0];              // 256 float4 contiguous
    red[l * 4 + 0] = make_float4(acc[0],  acc[1],  acc[2],  acc[3]);
    red[l * 4 + 1] = make_float4(acc[4],  acc[5],  acc[6],  acc[7]);
    red[l * 4 + 2] = make_float4(acc[8],  acc[9],  acc[10], acc[11]);
    red[l * 4 + 3] = make_float4(acc[12], acc[13], acc[14], acc[15]);
    __syncthreads();

    const int rr = t >> 2, qq = t & 3;       // thread -> (row, quad)
    const int grow = rbase + rr;
    if (grow < N_NODES) {
      const int s = rr * 4 + qq;
      const float4* p0 = &xs[0][0][0];
      const float4* p1 = &xs[1][0][0];
      const float4* p2 = &xs[2][0][0];
      const float4* p3 = &xs[3][0][0];
      float4 a = p0[s], b4 = p1[s], c4 = p2[s], d4 = p3[s];
      float4 o = make_float4(a.x + b4.x + c4.x + d4.x, a.y + b4.y + c4.y + d4.y,
                             a.z + b4.z + c4.z + d4.z, a.w + b4.w + c4.w + d4.w);
      ((float4*)xw)[(size_t)grow * 4 + qq] = o;
    }
  } else {
    // ---------------- binscatter role (stash-free) ----------------
    int* hist = (int*)smem;                       // 3.13 KB of the union
    const int e0 = (blockIdx.x >> 1) * CHUNK;
    const int nv = (N_EDGES - e0 < CHUNK) ? (N_EDGES - e0) : CHUNK;

    for (int b = t; b < NBUCK; b += 256) hist[b] = 0;
    __syncthreads();

    for (int i = t; i < nv; i += 256)
      atomicAdd(&hist[rows[e0 + i] >> 7], 1);     // LDS atomic
    __syncthreads();

    for (int b = t; b < NBUCK; b += 256) {
      const int h = hist[b];
      hist[b] = (h > 0) ? atomicAdd(&cursor[b], h) : 0;  // global, aggregated
    }
    __syncthreads();

    for (int i = t; i < nv; i += 256) {
      const int e = e0 + i;
      const int r = rows[e];
      const int b = r >> 7;
      const int off = atomicAdd(&hist[b], 1);     // LDS atomic: base + rank
      if (off < BCAP)
        binned[(size_t)b * BCAP + off] =
            make_int2(cols[e] | ((r & 127) << 20), __float_as_int(vals[e]));
    }
  }
}

// ---------------------------------------------------------------------------
// Per-bucket counting sort (low-LDS): rank via LDS-atomic histogram,
// 128-wide scan, re-read binned (LLC) and write row-sorted edges to binned2;
// emit row_beg/row_end. Zero global atomics.
__global__ __launch_bounds__(256)
void k_localcsr(const int2* __restrict__ binned, const int* __restrict__ cursor,
                int2* __restrict__ binned2, int* __restrict__ row_beg,
                int* __restrict__ row_end) {
  __shared__ unsigned short rk[BCAP];           // 10.25 KB
  __shared__ int hist[128];
  __shared__ int pfx[128];
  const int t = threadIdx.x;
  const int b = blockIdx.x;
  const int raw = cursor[b];
  const int cnt = raw < BCAP ? raw : BCAP;
  const int2* ep = binned + (size_t)b * BCAP;
  int2* eq = binned2 + (size_t)b * BCAP;

  if (t < 128) hist[t] = 0;
  __syncthreads();

  for (int i = t; i < cnt; i += 256) {
    const int row = (ep[i].x >> 20) & 127;
    rk[i] = (unsigned short)atomicAdd(&hist[row], 1);
  }
  __syncthreads();

  if (t < 128) pfx[t] = hist[t];
  __syncthreads();
#pragma unroll
  for (int off = 1; off < 128; off <<= 1) {     // inclusive Hillis-Steele
    int add = (t >= off && t < 128) ? pfx[t - off] : 0;
    __syncthreads();
    if (t < 128) pfx[t] += add;
    __syncthreads();
  }

  if (t < 128) {
    const int r = b * 128 + t;
    if (r < N_NODES) {
      const int beg = b * BCAP + pfx[t] - hist[t];      // exclusive prefix
      row_beg[r] = beg;
      row_end[r] = beg + hist[t];
    }
  }
  __syncthreads();

  for (int i = t; i < cnt; i += 256) {
    const int2 e = ep[i];                               // LLC re-read
    const int row = (e.x >> 20) & 127;
    eq[pfx[row] - hist[row] + (int)rk[i]] = e;
  }
}

// ---------------------------------------------------------------------------
// Fused layer-1 tail: gather-SPMM + bias + relu + (.) @ W2 -> hw1[r].
// 16 lanes per row (lane = hidden channel), 16 rows per 256-thread block.
// 4 independent FMA chains.
__global__ __launch_bounds__(256)
void k_fused1(const int2* __restrict__ binned2, const int* __restrict__ row_beg,
              const int* __restrict__ row_end, const float* __restrict__ xw,
              const float* __restrict__ b1, const float* __restrict__ W2,
              float* __restrict__ hw1) {
  const int t = threadIdx.x;
  const int lane16 = t & 15;
  const int r = blockIdx.x * 16 + (t >> 4);
  if (r >= N_NODES) return;
  const int s = row_beg[r], e = row_end[r];
  float a0 = 0.f, a1 = 0.f, a2 = 0.f, a3 = 0.f;
  int i = s;
  for (; i + 3 < e; i += 4) {                        // 4 independent chains
    int2 ea = binned2[i],     eb = binned2[i + 1];
    int2 ec = binned2[i + 2], ed = binned2[i + 3];
    a0 = fmaf(__int_as_float(ea.y), xw[(size_t)(ea.x & 0xFFFFF) * 16 + lane16], a0);
    a1 = fmaf(__int_as_float(eb.y), xw[(size_t)(eb.x & 0xFFFFF) * 16 + lane16], a1);
    a2 = fmaf(__int_as_float(ec.y), xw[(size_t)(ec.x & 0xFFFFF) * 16 + lane16], a2);
    a3 = fmaf(__int_as_float(ed.y), xw[(size_t)(ed.x & 0xFFFFF) * 16 + lane16], a3);
  }
  for (; i < e; ++i) {
    int2 ea = binned2[i];
    a0 = fmaf(__int_as_float(ea.y), xw[(size_t)(ea.x & 0xFFFFF) * 16 + lane16], a0);
  }
  float h = fmaxf((a0 + a1) + (a2 + a3) + b1[lane16], 0.f);
  float p = h * W2[lane16];
#pragma unroll
  for (int m = 8; m >= 1; m >>= 1) p += __shfl_xor(p, m, 16);
  if (lane16 == 0) hw1[r] = p;
}

// ---------------------------------------------------------------------------
// Fused layer-2 tail: gather-SPMM on scalars + bias + sigmoid -> out[r].
__global__ __launch_bounds__(256)
void k_fused2(const int2* __restrict__ binned2, const int* __restrict__ row_beg,
              const int* __restrict__ row_end, const float* __restrict__ hw1,
              const float* __restrict__ b2, float* __restrict__ out) {
  const int t = threadIdx.x;
  const int lane16 = t & 15;
  const int r = blockIdx.x * 16 + (t >> 4);
  if (r >= N_NODES) return;
  const int s = row_beg[r], e = row_end[r];
  float acc = 0.f;
  for (int i = s + lane16; i < e; i += 16) {
    int2 ev = binned2[i];
    acc = fmaf(__int_as_float(ev.y), hw1[ev.x & 0xFFFFF], acc);
  }
#pragma unroll
  for (int m = 8; m >= 1; m >>= 1) acc += __shfl_xor(acc, m, 16);
  if (lane16 == 0) out[r] = 1.f / (1.f + expf(-(acc + b2[0])));
}

// ---------------------------------------------------------------------------
extern "C" void kernel_launch(void* const* d_in, const int* in_sizes, int n_in,
                              void* d_out, int out_size, void* d_ws, size_t ws_size,
                              hipStream_t stream) {
  const float* x    = (const float*)d_in[0];
  const float* vals = (const float*)d_in[1];
  const float* W1   = (const float*)d_in[2];
  const float* b1   = (const float*)d_in[3];
  const float* W2   = (const float*)d_in[4];
  const float* b2   = (const float*)d_in[5];
  const int*   rows = (const int*)d_in[6];
  const int*   cols = (const int*)d_in[7];
  float* out = (float*)d_out;

  // workspace (~66 MB of the ~800 MB d_ws):
  // xw[N*16]f | binned[NBUCK*BCAP]int2 | binned2[NBUCK*BCAP]int2 |
  // cursor[NBUCK]i | row_beg[N]i | row_end[N]i | hw1[N]f
  char* w = (char*)d_ws;
  float* xw      = (float*)w;  w += (size_t)N_NODES * 16 * 4;
  int2*  binned  = (int2*)w;   w += (size_t)NBUCK * BCAP * 8;
  int2*  binned2 = (int2*)w;   w += (size_t)NBUCK * BCAP * 8;
  int*   cursor  = (int*)w;    w += (size_t)((NBUCK + 3) & ~3) * 4;
  int*   row_beg = (int*)w;    w += (size_t)N_NODES * 4;
  int*   row_end = (int*)w;    w += (size_t)N_NODES * 4;
  float* hw1     = (float*)w;

  k_prep    <<<(NBUCK + 255) / 256, 256, 0, stream>>>(cursor);
  k_mega3   <<<NGB + NBS,           256, 0, stream>>>(x, W1, xw, rows, cols, vals,
                                                      cursor, binned);
  k_localcsr<<<NBUCK,               256, 0, stream>>>(binned, cursor, binned2,
                                                      row_beg, row_end);
  k_fused1  <<<(N_NODES + 15) / 16, 256, 0, stream>>>(binned2, row_beg, row_end,
                                                      xw, b1, W2, hw1);
  k_fused2  <<<(N_NODES + 15) / 16, 256, 0, stream>>>(binned2, row_beg, row_end,
                                                      hw1, b2, out);
}

// Round 13
// 189.550 us; speedup vs baseline: 1.3010x; 1.3010x over previous
//
#include <hip/hip_runtime.h>
#include <cstdint>
#include <cstddef>

#define N_NODES 100000
#define N_EDGES 3200000
#define N_FEAT  512
#define HIDDEN  16
#define NBUCK   ((N_NODES + 127) / 128)   // 782 buckets of 128 rows
#define BCAP    5120                      // slots/bucket; mean 4092, +16 sigma
#define CHUNK   2048                      // edges per binscatter role-block
#define NGB     ((N_NODES + 63) / 64)     // 1563 gemm role-blocks (64 rows)
#define NBS     ((N_EDGES + CHUNK - 1) / CHUNK)  // 1563 binscatter role-blocks

static_assert(NGB == NBS, "parity interleave requires equal role counts");

// ---------------------------------------------------------------------------
// async global -> LDS, 16B per lane. LDS dest is wave-uniform base + lane*16.
__device__ __forceinline__ void gload_lds16(const float* g, void* lds) {
  __builtin_amdgcn_global_load_lds(
      (const __attribute__((address_space(1))) void*)g,
      (__attribute__((address_space(3))) void*)lds, 16, 0, 0);
}

// ---------------------------------------------------------------------------
// Prep: zero bucket cursors (replaces rocclr fillBuffer).
__global__ __launch_bounds__(256)
void k_prep(int* __restrict__ cursor) {
  const int i = blockIdx.x * 256 + threadIdx.x;
  if (i < NBUCK) cursor[i] = 0;
}

// ---------------------------------------------------------------------------
// MEGA2 (round-9 verbatim): parity-interleaved roles, co-resident from
// dispatch 0.  even blocks -> GEMM1, odd blocks -> binscatter.
// Union LDS = 32 KB -> 5 blocks/CU (~20 waves/CU).
//
// GEMM role: xw[r][c] = sum_k x[r][k]*W1[k][c]. 4 waves split K (128 each),
// K-chunk 16 floats (64 B/row = sector-aligned), per-wave double-buffered
// gload_lds stage, counted vmcnt(4), no intra-loop barriers; cross-wave LDS
// reduce at the end.
//
// binscatter role: bucket edges by row>>7. Per 2048-edge block: LDS stash +
// LDS histogram, ~780 block-aggregated global cursor atomics, then scatter
// of packed {col | (row&127)<<20, val_bits} into bucket slots.
__global__ __launch_bounds__(256)
void k_mega2(const float* __restrict__ x, const float* __restrict__ W1,
             float* __restrict__ xw, const int* __restrict__ rows,
             const int* __restrict__ cols, const float* __restrict__ vals,
             int* __restrict__ cursor, int2* __restrict__ binned) {
  __shared__ __align__(16) char smem[32768];
  const int t = threadIdx.x;

  if ((blockIdx.x & 1) == 0) {
    // ---------------- GEMM1 ----------------
    float4 (*xs)[2][256] = reinterpret_cast<float4 (*)[2][256]>(smem);
    const int l = t & 63;
    const int w = __builtin_amdgcn_readfirstlane(t >> 6);
    const int rbase = (blockIdx.x >> 1) * 64;
    const int kbase0 = w * 128;

    float acc[16];
#pragma unroll
    for (int c = 0; c < 16; ++c) acc[c] = 0.f;

    const int sq   = ((l & 3) ^ ((l >> 3) & 3)) * 4;  // source quad (floats)
    const int srow = l >> 2;

    auto STAGE = [&](int b, int ck) {
      const int kb = kbase0 + ck * 16;
#pragma unroll
      for (int i = 0; i < 4; ++i) {
        int grow = rbase + i * 16 + srow;
        if (grow >= N_NODES) grow = N_NODES - 1;      // clamp: fixed instr count
        gload_lds16(x + (size_t)grow * N_FEAT + kb + sq, &xs[w][b][i * 64]);
      }
    };

    const int rsw = (l >> 1) & 3;
    auto COMPUTE = [&](int b, int ck) {
      const int kb = kbase0 + ck * 16;
#pragma unroll
      for (int q = 0; q < 4; ++q) {
        float4 xv = xs[w][b][l * 4 + (q ^ rsw)];
        float xe[4] = {xv.x, xv.y, xv.z, xv.w};
#pragma unroll
        for (int j = 0; j < 4; ++j) {
          const float* wrow = W1 + (size_t)(kb + q * 4 + j) * 16; // s_load
#pragma unroll
          for (int c = 0; c < 16; ++c)
            acc[c] = fmaf(xe[j], wrow[c], acc[c]);
        }
      }
    };

    STAGE(0, 0);
#pragma unroll 1
    for (int ck = 0; ck < 8; ++ck) {
      const int b = ck & 1;
      if (ck + 1 < 8) {
        STAGE(b ^ 1, ck + 1);
        asm volatile("s_waitcnt vmcnt(4)" ::: "memory");
      } else {
        asm volatile("s_waitcnt vmcnt(0)" ::: "memory");
      }
      COMPUTE(b, ck);
    }

    float4* red = &xs[w][0][0];
    red[l * 4 + 0] = make_float4(acc[0],  acc[1],  acc[2],  acc[3]);
    red[l * 4 + 1] = make_float4(acc[4],  acc[5],  acc[6],  acc[7]);
    red[l * 4 + 2] = make_float4(acc[8],  acc[9],  acc[10], acc[11]);
    red[l * 4 + 3] = make_float4(acc[12], acc[13], acc[14], acc[15]);
    __syncthreads();

    const int rr = t >> 2, qq = t & 3;
    const int grow = rbase + rr;
    if (grow < N_NODES) {
      const int s = rr * 4 + qq;
      float4 a = xs[0][0][s], b4 = xs[1][0][s], c4 = xs[2][0][s], d4 = xs[3][0][s];
      float4 o = make_float4(a.x + b4.x + c4.x + d4.x, a.y + b4.y + c4.y + d4.y,
                             a.z + b4.z + c4.z + d4.z, a.w + b4.w + c4.w + d4.w);
      ((float4*)xw)[(size_t)grow * 4 + qq] = o;
    }
  } else {
    // ---------------- binscatter ----------------
    int2*           stash = (int2*)smem;                       // 16 KB
    unsigned short* sbuck = (unsigned short*)(smem + 16384);   // 4 KB
    int*            hist  = (int*)(smem + 16384 + 4096);       // 3.13 KB
    int*            base  = (int*)(smem + 16384 + 4096 + 4 * NBUCK);
    const int e0 = (blockIdx.x >> 1) * CHUNK;
    const int nv = (N_EDGES - e0 < CHUNK) ? (N_EDGES - e0) : CHUNK;

    for (int b = t; b < NBUCK; b += 256) hist[b] = 0;
    __syncthreads();

#pragma unroll
    for (int i = 0; i < CHUNK / 256; ++i) {
      const int idx = i * 256 + t;
      if (idx < nv) {
        const int e = e0 + idx;
        const int r = rows[e], c = cols[e];
        const float v = vals[e];
        const int b = r >> 7;
        stash[idx] = make_int2(c | ((r & 127) << 20), __float_as_int(v));
        sbuck[idx] = (unsigned short)b;
        atomicAdd(&hist[b], 1);                   // LDS atomic
      }
    }
    __syncthreads();

    for (int b = t; b < NBUCK; b += 256) {
      const int h = hist[b];
      base[b] = (h > 0) ? atomicAdd(&cursor[b], h) : 0;   // global, aggregated
      hist[b] = 0;                                         // reuse as rank ctr
    }
    __syncthreads();

#pragma unroll
    for (int i = 0; i < CHUNK / 256; ++i) {
      const int idx = i * 256 + t;
      if (idx < nv) {
        const int b = sbuck[idx];
        const int off = base[b] + atomicAdd(&hist[b], 1);  // LDS atomic
        if (off < BCAP) binned[(size_t)b * BCAP + off] = stash[idx];
      }
    }
  }
}

// ---------------------------------------------------------------------------
// Per-bucket counting sort (low-LDS): rank via LDS-atomic histogram,
// 128-wide scan, re-read binned (LLC) and write row-sorted edges to binned2;
// emit row_beg/row_end. Zero global atomics.
__global__ __launch_bounds__(256)
void k_localcsr(const int2* __restrict__ binned, const int* __restrict__ cursor,
                int2* __restrict__ binned2, int* __restrict__ row_beg,
                int* __restrict__ row_end) {
  __shared__ unsigned short rk[BCAP];           // 10.25 KB
  __shared__ int hist[128];
  __shared__ int pfx[128];
  const int t = threadIdx.x;
  const int b = blockIdx.x;
  const int raw = cursor[b];
  const int cnt = raw < BCAP ? raw : BCAP;
  const int2* ep = binned + (size_t)b * BCAP;
  int2* eq = binned2 + (size_t)b * BCAP;

  if (t < 128) hist[t] = 0;
  __syncthreads();

  for (int i = t; i < cnt; i += 256) {
    const int row = (ep[i].x >> 20) & 127;
    rk[i] = (unsigned short)atomicAdd(&hist[row], 1);
  }
  __syncthreads();

  if (t < 128) pfx[t] = hist[t];
  __syncthreads();
#pragma unroll
  for (int off = 1; off < 128; off <<= 1) {     // inclusive Hillis-Steele
    int add = (t >= off && t < 128) ? pfx[t - off] : 0;
    __syncthreads();
    if (t < 128) pfx[t] += add;
    __syncthreads();
  }

  if (t < 128) {
    const int r = b * 128 + t;
    if (r < N_NODES) {
      const int beg = b * BCAP + pfx[t] - hist[t];      // exclusive prefix
      row_beg[r] = beg;
      row_end[r] = beg + hist[t];
    }
  }
  __syncthreads();

  for (int i = t; i < cnt; i += 256) {
    const int2 e = ep[i];                               // LLC re-read
    const int row = (e.x >> 20) & 127;
    eq[pfx[row] - hist[row] + (int)rk[i]] = e;
  }
}

// ---------------------------------------------------------------------------
// Fused layer-1 tail: gather-SPMM + bias + relu + (.) @ W2 -> hw1[r].
// 16 lanes per row (lane = hidden channel), 16 rows per 256-thread block.
// 4 independent FMA chains.
__global__ __launch_bounds__(256)
void k_fused1(const int2* __restrict__ binned2, const int* __restrict__ row_beg,
              const int* __restrict__ row_end, const float* __restrict__ xw,
              const float* __restrict__ b1, const float* __restrict__ W2,
              float* __restrict__ hw1) {
  const int t = threadIdx.x;
  const int lane16 = t & 15;
  const int r = blockIdx.x * 16 + (t >> 4);
  if (r >= N_NODES) return;
  const int s = row_beg[r], e = row_end[r];
  float a0 = 0.f, a1 = 0.f, a2 = 0.f, a3 = 0.f;
  int i = s;
  for (; i + 3 < e; i += 4) {                        // 4 independent chains
    int2 ea = binned2[i],     eb = binned2[i + 1];
    int2 ec = binned2[i + 2], ed = binned2[i + 3];
    a0 = fmaf(__int_as_float(ea.y), xw[(size_t)(ea.x & 0xFFFFF) * 16 + lane16], a0);
    a1 = fmaf(__int_as_float(eb.y), xw[(size_t)(eb.x & 0xFFFFF) * 16 + lane16], a1);
    a2 = fmaf(__int_as_float(ec.y), xw[(size_t)(ec.x & 0xFFFFF) * 16 + lane16], a2);
    a3 = fmaf(__int_as_float(ed.y), xw[(size_t)(ed.x & 0xFFFFF) * 16 + lane16], a3);
  }
  for (; i < e; ++i) {
    int2 ea = binned2[i];
    a0 = fmaf(__int_as_float(ea.y), xw[(size_t)(ea.x & 0xFFFFF) * 16 + lane16], a0);
  }
  float h = fmaxf((a0 + a1) + (a2 + a3) + b1[lane16], 0.f);
  float p = h * W2[lane16];
#pragma unroll
  for (int m = 8; m >= 1; m >>= 1) p += __shfl_xor(p, m, 16);
  if (lane16 == 0) hw1[r] = p;
}

// ---------------------------------------------------------------------------
// Fused layer-2 tail: gather-SPMM on scalars + bias + sigmoid -> out[r].
__global__ __launch_bounds__(256)
void k_fused2(const int2* __restrict__ binned2, const int* __restrict__ row_beg,
              const int* __restrict__ row_end, const float* __restrict__ hw1,
              const float* __restrict__ b2, float* __restrict__ out) {
  const int t = threadIdx.x;
  const int lane16 = t & 15;
  const int r = blockIdx.x * 16 + (t >> 4);
  if (r >= N_NODES) return;
  const int s = row_beg[r], e = row_end[r];
  float acc = 0.f;
  for (int i = s + lane16; i < e; i += 16) {
    int2 ev = binned2[i];
    acc = fmaf(__int_as_float(ev.y), hw1[ev.x & 0xFFFFF], acc);
  }
#pragma unroll
  for (int m = 8; m >= 1; m >>= 1) acc += __shfl_xor(acc, m, 16);
  if (lane16 == 0) out[r] = 1.f / (1.f + expf(-(acc + b2[0])));
}

// ---------------------------------------------------------------------------
extern "C" void kernel_launch(void* const* d_in, const int* in_sizes, int n_in,
                              void* d_out, int out_size, void* d_ws, size_t ws_size,
                              hipStream_t stream) {
  const float* x    = (const float*)d_in[0];
  const float* vals = (const float*)d_in[1];
  const float* W1   = (const float*)d_in[2];
  const float* b1   = (const float*)d_in[3];
  const float* W2   = (const float*)d_in[4];
  const float* b2   = (const float*)d_in[5];
  const int*   rows = (const int*)d_in[6];
  const int*   cols = (const int*)d_in[7];
  float* out = (float*)d_out;

  // workspace (~66 MB of the ~800 MB d_ws):
  // xw[N*16]f | binned[NBUCK*BCAP]int2 | binned2[NBUCK*BCAP]int2 |
  // cursor[NBUCK]i | row_beg[N]i | row_end[N]i | hw1[N]f
  char* w = (char*)d_ws;
  float* xw      = (float*)w;  w += (size_t)N_NODES * 16 * 4;
  int2*  binned  = (int2*)w;   w += (size_t)NBUCK * BCAP * 8;
  int2*  binned2 = (int2*)w;   w += (size_t)NBUCK * BCAP * 8;
  int*   cursor  = (int*)w;    w += (size_t)((NBUCK + 3) & ~3) * 4;
  int*   row_beg = (int*)w;    w += (size_t)N_NODES * 4;
  int*   row_end = (int*)w;    w += (size_t)N_NODES * 4;
  float* hw1     = (float*)w;

  k_prep    <<<(NBUCK + 255) / 256, 256, 0, stream>>>(cursor);
  k_mega2   <<<NGB + NBS,           256, 0, stream>>>(x, W1, xw, rows, cols, vals,
                                                      cursor, binned);
  k_localcsr<<<NBUCK,               256, 0, stream>>>(binned, cursor, binned2,
                                                      row_beg, row_end);
  k_fused1  <<<(N_NODES + 15) / 16, 256, 0, stream>>>(binned2, row_beg, row_end,
                                                      xw, b1, W2, hw1);
  k_fused2  <<<(N_NODES + 15) / 16, 256, 0, stream>>>(binned2, row_beg, row_end,
                                                      hw1, b2, out);
}

// Round 14
// 155.502 us; speedup vs baseline: 1.5858x; 1.2190x over previous
//
#include <hip/hip_runtime.h>
#include <cstdint>
#include <cstddef>

#define N_NODES 100000
#define N_EDGES 3200000
#define N_FEAT  512
#define HIDDEN  16
#define NBUCK   ((N_NODES + 127) / 128)   // 782 buckets of 128 rows
#define BCAP    4608                      // slots/bucket; mean 4092, +8 sigma
#define CHUNK   2048                      // edges per binscatter role-block
#define NGB     ((N_NODES + 63) / 64)     // 1563 gemm role-blocks (64 rows)
#define NBS     ((N_EDGES + CHUNK - 1) / CHUNK)  // 1563 binscatter role-blocks
#define AGG_T   512

static_assert(NGB == NBS, "parity interleave requires equal role counts");

// ---------------------------------------------------------------------------
// async global -> LDS, 16B per lane. LDS dest is wave-uniform base + lane*16.
__device__ __forceinline__ void gload_lds16(const float* g, void* lds) {
  __builtin_amdgcn_global_load_lds(
      (const __attribute__((address_space(1))) void*)g,
      (__attribute__((address_space(3))) void*)lds, 16, 0, 0);
}

// ---------------------------------------------------------------------------
// Prep: zero bucket cursors (replaces rocclr fillBuffer).
__global__ __launch_bounds__(256)
void k_prep(int* __restrict__ cursor) {
  const int i = blockIdx.x * 256 + threadIdx.x;
  if (i < NBUCK) cursor[i] = 0;
}

// ---------------------------------------------------------------------------
// MEGA2 (round-9 verbatim): parity-interleaved roles, co-resident from
// dispatch 0.  even blocks -> GEMM1, odd blocks -> binscatter.
// Union LDS = 32 KB -> 5 blocks/CU (~20 waves/CU).
__global__ __launch_bounds__(256)
void k_mega2(const float* __restrict__ x, const float* __restrict__ W1,
             float* __restrict__ xw, const int* __restrict__ rows,
             const int* __restrict__ cols, const float* __restrict__ vals,
             int* __restrict__ cursor, int2* __restrict__ binned) {
  __shared__ __align__(16) char smem[32768];
  const int t = threadIdx.x;

  if ((blockIdx.x & 1) == 0) {
    // ---------------- GEMM1 ----------------
    float4 (*xs)[2][256] = reinterpret_cast<float4 (*)[2][256]>(smem);
    const int l = t & 63;
    const int w = __builtin_amdgcn_readfirstlane(t >> 6);
    const int rbase = (blockIdx.x >> 1) * 64;
    const int kbase0 = w * 128;

    float acc[16];
#pragma unroll
    for (int c = 0; c < 16; ++c) acc[c] = 0.f;

    const int sq   = ((l & 3) ^ ((l >> 3) & 3)) * 4;  // source quad (floats)
    const int srow = l >> 2;

    auto STAGE = [&](int b, int ck) {
      const int kb = kbase0 + ck * 16;
#pragma unroll
      for (int i = 0; i < 4; ++i) {
        int grow = rbase + i * 16 + srow;
        if (grow >= N_NODES) grow = N_NODES - 1;      // clamp: fixed instr count
        gload_lds16(x + (size_t)grow * N_FEAT + kb + sq, &xs[w][b][i * 64]);
      }
    };

    const int rsw = (l >> 1) & 3;
    auto COMPUTE = [&](int b, int ck) {
      const int kb = kbase0 + ck * 16;
#pragma unroll
      for (int q = 0; q < 4; ++q) {
        float4 xv = xs[w][b][l * 4 + (q ^ rsw)];
        float xe[4] = {xv.x, xv.y, xv.z, xv.w};
#pragma unroll
        for (int j = 0; j < 4; ++j) {
          const float* wrow = W1 + (size_t)(kb + q * 4 + j) * 16; // s_load
#pragma unroll
          for (int c = 0; c < 16; ++c)
            acc[c] = fmaf(xe[j], wrow[c], acc[c]);
        }
      }
    };

    STAGE(0, 0);
#pragma unroll 1
    for (int ck = 0; ck < 8; ++ck) {
      const int b = ck & 1;
      if (ck + 1 < 8) {
        STAGE(b ^ 1, ck + 1);
        asm volatile("s_waitcnt vmcnt(4)" ::: "memory");
      } else {
        asm volatile("s_waitcnt vmcnt(0)" ::: "memory");
      }
      COMPUTE(b, ck);
    }

    float4* red = &xs[w][0][0];
    red[l * 4 + 0] = make_float4(acc[0],  acc[1],  acc[2],  acc[3]);
    red[l * 4 + 1] = make_float4(acc[4],  acc[5],  acc[6],  acc[7]);
    red[l * 4 + 2] = make_float4(acc[8],  acc[9],  acc[10], acc[11]);
    red[l * 4 + 3] = make_float4(acc[12], acc[13], acc[14], acc[15]);
    __syncthreads();

    const int rr = t >> 2, qq = t & 3;
    const int grow = rbase + rr;
    if (grow < N_NODES) {
      const int s = rr * 4 + qq;
      float4 a = xs[0][0][s], b4 = xs[1][0][s], c4 = xs[2][0][s], d4 = xs[3][0][s];
      float4 o = make_float4(a.x + b4.x + c4.x + d4.x, a.y + b4.y + c4.y + d4.y,
                             a.z + b4.z + c4.z + d4.z, a.w + b4.w + c4.w + d4.w);
      ((float4*)xw)[(size_t)grow * 4 + qq] = o;
    }
  } else {
    // ---------------- binscatter ----------------
    int2*           stash = (int2*)smem;                       // 16 KB
    unsigned short* sbuck = (unsigned short*)(smem + 16384);   // 4 KB
    int*            hist  = (int*)(smem + 16384 + 4096);       // 3.13 KB
    int*            base  = (int*)(smem + 16384 + 4096 + 4 * NBUCK);
    const int e0 = (blockIdx.x >> 1) * CHUNK;
    const int nv = (N_EDGES - e0 < CHUNK) ? (N_EDGES - e0) : CHUNK;

    for (int b = t; b < NBUCK; b += 256) hist[b] = 0;
    __syncthreads();

#pragma unroll
    for (int i = 0; i < CHUNK / 256; ++i) {
      const int idx = i * 256 + t;
      if (idx < nv) {
        const int e = e0 + idx;
        const int r = rows[e], c = cols[e];
        const float v = vals[e];
        const int b = r >> 7;
        stash[idx] = make_int2(c | ((r & 127) << 20), __float_as_int(v));
        sbuck[idx] = (unsigned short)b;
        atomicAdd(&hist[b], 1);                   // LDS atomic
      }
    }
    __syncthreads();

    for (int b = t; b < NBUCK; b += 256) {
      const int h = hist[b];
      base[b] = (h > 0) ? atomicAdd(&cursor[b], h) : 0;   // global, aggregated
      hist[b] = 0;                                         // reuse as rank ctr
    }
    __syncthreads();

#pragma unroll
    for (int i = 0; i < CHUNK / 256; ++i) {
      const int idx = i * 256 + t;
      if (idx < nv) {
        const int b = sbuck[idx];
        const int off = base[b] + atomicAdd(&hist[b], 1);  // LDS atomic
        if (off < BCAP) binned[(size_t)b * BCAP + off] = stash[idx];
      }
    }
  }
}

// ---------------------------------------------------------------------------
// SORTAGG: per bucket (128 rows, 512 thr, 37.5 KB LDS -> 4 blocks/CU):
//  A) hist of rows (LDS atomics) from binned (cold read)
//  B) 128-wide scan -> inc; emit row_beg/row_end (for fused2)
//  C) placement: rank via cnt2 LDS atomics, sorted edges into LDS stash
//     (re-read of binned is L2-hot)
//  D) stream stash -> binned2 (for fused2; stores drain under compute)
//  E) hw1 = relu(agg + b1) @ W2 via 16-lane groups, 4 chains; per-edge
//     descriptors are LDS BROADCAST reads (all 16 lanes same slot).
// Replaces localcsr + fused1: kills 51 MB of binned2 round-trip traffic
// for the layer-1 path and one kernel launch.
__global__ __launch_bounds__(AGG_T)
void k_sortagg(const int2* __restrict__ binned, const int* __restrict__ cursor,
               int2* __restrict__ binned2, int* __restrict__ row_beg,
               int* __restrict__ row_end, const float* __restrict__ xw,
               const float* __restrict__ b1, const float* __restrict__ W2,
               float* __restrict__ hw1) {
  __shared__ int2 stash[BCAP];                  // 36 KB
  __shared__ int hist[128];
  __shared__ int inc[128];
  __shared__ int cnt2[128];
  const int t = threadIdx.x;
  const int b = blockIdx.x;
  const int raw = cursor[b];
  const int cnt = raw < BCAP ? raw : BCAP;
  const int2* ep = binned + (size_t)b * BCAP;

  if (t < 128) { hist[t] = 0; cnt2[t] = 0; }
  __syncthreads();

  for (int i = t; i < cnt; i += AGG_T)
    atomicAdd(&hist[(ep[i].x >> 20) & 127], 1);         // LDS atomic
  __syncthreads();

  if (t < 128) inc[t] = hist[t];
  __syncthreads();
#pragma unroll
  for (int off = 1; off < 128; off <<= 1) {             // inclusive scan
    int add = (t >= off && t < 128) ? inc[t - off] : 0;
    __syncthreads();
    if (t < 128) inc[t] += add;
    __syncthreads();
  }

  if (t < 128) {
    const int r = b * 128 + t;
    if (r < N_NODES) {
      row_beg[r] = b * BCAP + inc[t] - hist[t];
      row_end[r] = b * BCAP + inc[t];
    }
  }
  // (scan loop's trailing __syncthreads ordered inc/hist for everyone)

  for (int i = t; i < cnt; i += AGG_T) {                // placement
    const int2 e = ep[i];                               // L2-hot re-read
    const int row = (e.x >> 20) & 127;
    const int off = inc[row] - hist[row] + atomicAdd(&cnt2[row], 1);
    stash[off] = e;
  }
  __syncthreads();

  int2* eq = binned2 + (size_t)b * BCAP;                // writeback for fused2
  for (int i = t; i < cnt; i += AGG_T) eq[i] = stash[i];

  // ---- layer-1 MLP from LDS descriptors ----
  const int lane16 = t & 15;
  const int g = t >> 4;                                 // 0..31
  const float bb = b1[lane16];
  const float ww = W2[lane16];
#pragma unroll 1
  for (int rr = g; rr < 128; rr += 32) {
    const int r = b * 128 + rr;
    if (r >= N_NODES) continue;
    const int s = inc[rr] - hist[rr], e2 = inc[rr];
    float a0 = 0.f, a1 = 0.f, a2 = 0.f, a3 = 0.f;
    int i = s;
    for (; i + 3 < e2; i += 4) {                        // 4 independent chains
      int2 ea = stash[i],     eb = stash[i + 1];        // LDS broadcast
      int2 ec = stash[i + 2], ed = stash[i + 3];
      a0 = fmaf(__int_as_float(ea.y), xw[(size_t)(ea.x & 0xFFFFF) * 16 + lane16], a0);
      a1 = fmaf(__int_as_float(eb.y), xw[(size_t)(eb.x & 0xFFFFF) * 16 + lane16], a1);
      a2 = fmaf(__int_as_float(ec.y), xw[(size_t)(ec.x & 0xFFFFF) * 16 + lane16], a2);
      a3 = fmaf(__int_as_float(ed.y), xw[(size_t)(ed.x & 0xFFFFF) * 16 + lane16], a3);
    }
    for (; i < e2; ++i) {
      int2 ea = stash[i];
      a0 = fmaf(__int_as_float(ea.y), xw[(size_t)(ea.x & 0xFFFFF) * 16 + lane16], a0);
    }
    float h = fmaxf((a0 + a1) + (a2 + a3) + bb, 0.f);
    float p = h * ww;
#pragma unroll
    for (int m = 8; m >= 1; m >>= 1) p += __shfl_xor(p, m, 16);
    if (lane16 == 0) hw1[r] = p;
  }
}

// ---------------------------------------------------------------------------
// Fused layer-2 tail: gather-SPMM on scalars + bias + sigmoid -> out[r].
__global__ __launch_bounds__(256)
void k_fused2(const int2* __restrict__ binned2, const int* __restrict__ row_beg,
              const int* __restrict__ row_end, const float* __restrict__ hw1,
              const float* __restrict__ b2, float* __restrict__ out) {
  const int t = threadIdx.x;
  const int lane16 = t & 15;
  const int r = blockIdx.x * 16 + (t >> 4);
  if (r >= N_NODES) return;
  const int s = row_beg[r], e = row_end[r];
  float acc = 0.f;
  for (int i = s + lane16; i < e; i += 16) {
    int2 ev = binned2[i];
    acc = fmaf(__int_as_float(ev.y), hw1[ev.x & 0xFFFFF], acc);
  }
#pragma unroll
  for (int m = 8; m >= 1; m >>= 1) acc += __shfl_xor(acc, m, 16);
  if (lane16 == 0) out[r] = 1.f / (1.f + expf(-(acc + b2[0])));
}

// ---------------------------------------------------------------------------
extern "C" void kernel_launch(void* const* d_in, const int* in_sizes, int n_in,
                              void* d_out, int out_size, void* d_ws, size_t ws_size,
                              hipStream_t stream) {
  const float* x    = (const float*)d_in[0];
  const float* vals = (const float*)d_in[1];
  const float* W1   = (const float*)d_in[2];
  const float* b1   = (const float*)d_in[3];
  const float* W2   = (const float*)d_in[4];
  const float* b2   = (const float*)d_in[5];
  const int*   rows = (const int*)d_in[6];
  const int*   cols = (const int*)d_in[7];
  float* out = (float*)d_out;

  // workspace (~60 MB of the ~800 MB d_ws):
  // xw[N*16]f | binned[NBUCK*BCAP]int2 | binned2[NBUCK*BCAP]int2 |
  // cursor[NBUCK]i | row_beg[N]i | row_end[N]i | hw1[N]f
  char* w = (char*)d_ws;
  float* xw      = (float*)w;  w += (size_t)N_NODES * 16 * 4;
  int2*  binned  = (int2*)w;   w += (size_t)NBUCK * BCAP * 8;
  int2*  binned2 = (int2*)w;   w += (size_t)NBUCK * BCAP * 8;
  int*   cursor  = (int*)w;    w += (size_t)((NBUCK + 3) & ~3) * 4;
  int*   row_beg = (int*)w;    w += (size_t)N_NODES * 4;
  int*   row_end = (int*)w;    w += (size_t)N_NODES * 4;
  float* hw1     = (float*)w;

  k_prep    <<<(NBUCK + 255) / 256, 256,   0, stream>>>(cursor);
  k_mega2   <<<NGB + NBS,           256,   0, stream>>>(x, W1, xw, rows, cols,
                                                        vals, cursor, binned);
  k_sortagg <<<NBUCK,               AGG_T, 0, stream>>>(binned, cursor, binned2,
                                                        row_beg, row_end, xw,
                                                        b1, W2, hw1);
  k_fused2  <<<(N_NODES + 15) / 16, 256,   0, stream>>>(binned2, row_beg, row_end,
                                                        hw1, b2, out);
}